// Round 7
// baseline (465.153 us; speedup 1.0000x reference)
//
#include <hip/hip_runtime.h>

typedef unsigned short u16;
typedef __attribute__((ext_vector_type(4))) unsigned short u16x4;
typedef __attribute__((ext_vector_type(8))) short short8;
typedef __attribute__((ext_vector_type(16))) float f32x16;

#define MFMA(a,b,c) __builtin_amdgcn_mfma_f32_32x32x16_bf16((a),(b),(c),0,0,0)

// ---- output offsets (floats), reference return order ----
static constexpr size_t OFF_XOUT = 0;
static constexpr size_t OFF_Z    = 16777216;
static constexpr size_t OFF_ZHAT = 20971520;
static constexpr size_t OFF_SUR  = 25165824;
static constexpr size_t OFF_KC   = 25296896;
static constexpr size_t OFF_VP   = 42074112;
static constexpr size_t OFF_GATE = 58851328;
static constexpr size_t OFF_QN   = 58982400;
static constexpr size_t OFF_VC   = 75759616;
static constexpr size_t OFF_WN   = 92536832;
static constexpr size_t OFF_S5   = 92667904;

// ---- workspace offsets (u16 elements): transposed bf16 weights ----
static constexpr size_t WUP_T = 0;          // [G][512][128]
static constexpr size_t WDN_T = 4194304;    // [G][128][512]
static constexpr size_t WPO_T = 8388608;    // [G][513][128]
static constexpr size_t WEN_T = 12591104;   // [G][32][128]
static constexpr size_t WGN_T = 12853248;   // [G][128][32]
static constexpr size_t WPR_T = 13115392;   // [G][32][32]

__device__ __forceinline__ u16 f2b(float f) {
    unsigned u = __float_as_uint(f);
    unsigned r = (u + 0x7FFFu + ((u >> 16) & 1u)) >> 16;
    return (u16)r;
}
__device__ __forceinline__ float b2f(u16 b) {
    return __uint_as_float(((unsigned)b) << 16);
}
// swizzles for [R][128]bf16 (256B rows) and [R][32]bf16 (64B rows)
__device__ __forceinline__ int swz256(int row, int b) {
    return row * 256 + (b ^ ((row & 7) << 4) ^ (((row >> 3) & 1) << 7));
}
__device__ __forceinline__ int swz64(int row, int b) {
    return row * 64 + (b ^ ((row & 3) << 4));
}
// A/B fragment loads for mfma_f32_32x32x16_bf16: lane holds 8 contiguous k,
// row/col = lane&31, k-half = lane>>5.
__device__ __forceinline__ short8 fragLd256(const u16* s, int row, int ks) {
    int b = ks * 32 + ((threadIdx.x >> 5) & 1) * 16;
    return *(const short8*)((const char*)s + swz256(row, b));
}
__device__ __forceinline__ short8 fragLd64(const u16* s, int row, int ks) {
    int b = ks * 32 + ((threadIdx.x >> 5) & 1) * 16;
    return *(const short8*)((const char*)s + swz64(row, b));
}
__device__ __forceinline__ float tanh_f(float x) {
    float xc = fminf(fmaxf(x, -15.f), 15.f);
    float e = __expf(2.f * xc);
    return __fdividef(e - 1.f, e + 1.f);
}
__device__ __forceinline__ float gelu_f(float u) {
    float y = 0.7978845608f * (u + 0.044715f * u * u * u);
    return 0.5f * u * (1.f + tanh_f(y));
}

// ---------------- fused transpose+convert for all six weights ----------------
// src[G][K][C] f32 -> dst[G][C][K] bf16
__global__ __launch_bounds__(256)
void kconv_all(const float* __restrict__ W_up, const float* __restrict__ W_down,
               const float* __restrict__ W_post, const float* __restrict__ W_enc,
               const float* __restrict__ W_gain, const float* __restrict__ W_pred,
               u16* __restrict__ ws)
{
    int b = blockIdx.x;
    const float* src; u16* dst; int K, C, bx;
    if (b < 1024)      { src = W_up;   dst = ws + WUP_T; K = 128; C = 512; bx = 8; }
    else if (b < 2048) { b -= 1024; src = W_down; dst = ws + WDN_T; K = 512; C = 128; bx = 2; }
    else if (b < 3200) { b -= 2048; src = W_post; dst = ws + WPO_T; K = 128; C = 513; bx = 9; }
    else if (b < 3328) { b -= 3200; src = W_enc;  dst = ws + WEN_T; K = 128; C = 32;  bx = 1; }
    else if (b < 3456) { b -= 3328; src = W_gain; dst = ws + WGN_T; K = 32;  C = 128; bx = 2; }
    else               { b -= 3456; src = W_pred; dst = ws + WPR_T; K = 32;  C = 32;  bx = 1; }
    const int by = (K + 63) >> 6;
    const int nb = bx * by;
    const int g = b / nb, r = b % nb;
    const int c0 = (r % bx) * 64, k0 = (r / bx) * 64;

    __shared__ float sT[64][65];
    const float* s = src + (size_t)g * K * C;
    u16* d = dst + (size_t)g * K * C;
    for (int e = threadIdx.x; e < 64 * 64; e += 256) {
        int kk = e >> 6, cc = e & 63;
        if (k0 + kk < K && c0 + cc < C)
            sT[kk][cc] = s[(size_t)(k0 + kk) * C + c0 + cc];
    }
    __syncthreads();
    for (int e = threadIdx.x; e < 64 * 64; e += 256) {
        int cc = e >> 6, kk = e & 63;
        if (k0 + kk < K && c0 + cc < C)
            d[(size_t)(c0 + cc) * K + k0 + kk] = f2b(sT[kk][cc]);
    }
}

// ---------------- fully fused main kernel: 64-token tile, 512 threads ----------------
// LDS ~66KB -> 2 independent blocks/CU (cross-block latency hiding).
__global__ __launch_bounds__(512, 4)
void kfused(const float* __restrict__ x_col,
            const float* __restrict__ z_hat_prev,
            const float* __restrict__ gamma,
            const float* __restrict__ beta,
            const float* __restrict__ b_enc,
            const float* __restrict__ b_pred,
            const float* __restrict__ b_gain,
            const float* __restrict__ b_up,
            const float* __restrict__ b_down,
            const float* __restrict__ b_post,
            const u16* __restrict__ ws,
            float* __restrict__ out)
{
    // XCD-aware mapping: same residue (bid&7) covers 8 consecutive groups.
    const int bid = blockIdx.x;
    const int xc = bid & 7, j = bid >> 3;       // j 0..255
    const int g = xc * 8 + (j >> 5);
    const int tile = j & 31;
    const int m0 = tile * 64;

    const int tid = threadIdx.x, lane = tid & 63;
    const int w8 = tid >> 6;                 // wave 0..7
    const int wr = w8 >> 2;                  // row frag (32 rows), 0..1
    const int wc = w8 & 3;                   // col frag (32 cols), 0..3
    const int l31 = lane & 31, lh = lane >> 5;

    __shared__ u16 sXH[64 * 128];   // 16KB: x bf16 -> h (in-place) -> x_out bf16
    __shared__ u16 sW[128 * 128];   // 32KB: weight staging
    __shared__ u16 sU[64 * 128];    // 16KB: A: D/Z; B: gelu out
    __shared__ float sMu[64], sRstd[64], sInv[64], sNov[128];
    __shared__ float sNrm2[64][4];

    const u16* wPo = ws + WPO_T + (size_t)g * 65664;

    // small weights packed inside sW (u16-element offsets):
    u16* sWe = sW;              // bytes [0,8192): Wenc^T [32][128] swz256
    u16* sWg = sW + 4096;       // bytes [8192,16384): Wgain^T [128][32] swz64
    u16* sWp = sW + 8192;       // bytes [16384,18432): Wpred^T [32][32] swz64
    u16* sD  = sU;              // [64][32] swz64, bytes [0,4096)
    u16* sZ  = sU + 2048;       // [64][32] swz64, bytes [4096,8192)

    // residual fragment in registers (f32, exact)
    float xres[16];
    {
        const int jc = 32 * wc + l31;
        #pragma unroll
        for (int r = 0; r < 16; ++r) {
            int row = 32 * wr + (r & 3) + 8 * (r >> 2) + 4 * lh;
            xres[r] = x_col[(size_t)(m0 + row) * 8192 + g * 128 + jc];
        }
    }

    // ---- staging ----
    for (int idx = tid; idx < 64 * 32; idx += 512) {
        int row = idx >> 5, q = idx & 31;
        float4 v = *(const float4*)&x_col[(size_t)(m0 + row) * 8192 + g * 128 + q * 4];
        u16x4 bv; bv.x = f2b(v.x); bv.y = f2b(v.y); bv.z = f2b(v.z); bv.w = f2b(v.w);
        *(u16x4*)((char*)sXH + swz256(row, q * 8)) = bv;
    }
    {   // Wenc^T: 32 rows x 16 slots = 512
        int row = tid >> 4, slot = tid & 15;
        short8 v = *(const short8*)(ws + WEN_T + ((size_t)g * 32 + row) * 128 + slot * 8);
        *(short8*)((char*)sWe + swz256(row, slot * 16)) = v;
    }
    {   // Wgain^T: 128 rows x 4 slots = 512
        int row = tid >> 2, slot = tid & 3;
        short8 v = *(const short8*)(ws + WGN_T + ((size_t)g * 128 + row) * 32 + slot * 8);
        *(short8*)((char*)sWg + swz64(row, slot * 16)) = v;
    }
    if (tid < 128) {
        int row = tid >> 2, slot = tid & 3;
        short8 v = *(const short8*)(ws + WPR_T + ((size_t)g * 32 + row) * 32 + slot * 8);
        *(short8*)((char*)sWp + swz64(row, slot * 16)) = v;
        sNov[tid] = b2f(wPo[(size_t)512 * 128 + tid]);
    }
    __syncthreads();

    // ---- phase A step 1: {waves 0-1: enc GEMM} || {waves 2-3: LN stats} ----
    if (w8 < 2) {
        f32x16 zacc = (f32x16)0.f;
        #pragma unroll
        for (int ks = 0; ks < 8; ++ks) {
            short8 a = fragLd256(sXH, 32 * w8 + l31, ks);
            short8 b = fragLd256(sWe, l31, ks);
            zacc = MFMA(a, b, zacc);
        }
        float benc = b_enc[g * 32 + l31];
        #pragma unroll
        for (int r = 0; r < 16; ++r) {
            float zv = zacc[r] + benc;
            int row = 32 * w8 + (r & 3) + 8 * (r >> 2) + 4 * lh;
            size_t zoff = (size_t)(m0 + row) * 2048 + g * 32 + l31;
            out[OFF_Z + zoff] = zv;
            float d = zv - z_hat_prev[zoff];
            *(u16*)((char*)sD + swz64(row, l31 * 2)) = f2b(d);
            *(u16*)((char*)sZ + swz64(row, l31 * 2)) = f2b(zv);
            float ss = d * d;
            ss += __shfl_xor(ss, 1); ss += __shfl_xor(ss, 2); ss += __shfl_xor(ss, 4);
            ss += __shfl_xor(ss, 8); ss += __shfl_xor(ss, 16);
            if (l31 == 0) {
                float sur = sqrtf(ss);
                size_t p = (size_t)(m0 + row) * 64 + g;
                out[OFF_SUR + p] = sur;
                out[OFF_S5 + p] = sur;
                out[OFF_GATE + p] = fminf(fmaxf(sur, 0.f), 1.f);
            }
        }
    } else if (w8 < 4) {
        int t = tid - 128;                  // 0..127
        int row = t >> 1, half = t & 1;
        float s1 = 0.f, s2 = 0.f;
        #pragma unroll
        for (int i = 0; i < 8; ++i) {
            short8 v = *(const short8*)((const char*)sXH + swz256(row, (half * 64 + i * 8) * 2));
            #pragma unroll
            for (int jj = 0; jj < 8; ++jj) { float x = b2f((u16)v[jj]); s1 += x; s2 += x * x; }
        }
        s1 += __shfl_xor(s1, 1); s2 += __shfl_xor(s2, 1);
        if (half == 0) {
            float mu = s1 * (1.f / 128.f);
            float var = s2 * (1.f / 128.f) - mu * mu;
            sMu[row] = mu; sRstd[row] = rsqrtf(var + 1e-5f);
        }
    }
    __syncthreads();

    // ---- phase A step 2: {waves 0-3: gain + LN apply (in-place x->h)} || {waves 4-5: pred} ----
    if (w8 < 4) {
        const int wrg = w8 >> 1;       // row frag
        const int cp  = w8 & 1;        // col pair: frags {2cp, 2cp+1}
        f32x16 gacc[2];
        gacc[0] = (f32x16)0.f; gacc[1] = (f32x16)0.f;
        #pragma unroll
        for (int ks = 0; ks < 2; ++ks) {
            short8 a = fragLd64(sD, 32 * wrg + l31, ks);
            #pragma unroll
            for (int k = 0; k < 2; ++k) {
                short8 b = fragLd64(sWg, 32 * (2 * cp + k) + l31, ks);
                gacc[k] = MFMA(a, b, gacc[k]);
            }
        }
        #pragma unroll
        for (int k = 0; k < 2; ++k) {
            int col = 32 * (2 * cp + k) + l31;
            float bg = b_gain[g * 128 + col];
            float gam = gamma[g * 128 + col];
            float bet = beta[g * 128 + col];
            #pragma unroll
            for (int r = 0; r < 16; ++r) {
                int row = 32 * wrg + (r & 3) + 8 * (r >> 2) + 4 * lh;
                float gain = 1.f + 0.1f * tanh_f(gacc[k][r] + bg);
                float xv = b2f(*(const u16*)((const char*)sXH + swz256(row, col * 2)));
                float h = ((xv - sMu[row]) * sRstd[row] * gam + bet) * gain;
                *(u16*)((char*)sXH + swz256(row, col * 2)) = f2b(h);   // in-place
            }
        }
    } else if (w8 < 6) {
        int wp = w8 - 4;
        f32x16 pacc = (f32x16)0.f;
        #pragma unroll
        for (int ks = 0; ks < 2; ++ks) {
            short8 a = fragLd64(sZ, 32 * wp + l31, ks);
            short8 b = fragLd64(sWp, l31, ks);
            pacc = MFMA(a, b, pacc);
        }
        float bpred = b_pred[g * 32 + l31];
        #pragma unroll
        for (int r = 0; r < 16; ++r) {
            int row = 32 * wp + (r & 3) + 8 * (r >> 2) + 4 * lh;
            out[OFF_ZHAT + (size_t)(m0 + row) * 2048 + g * 32 + l31] = pacc[r] + bpred;
        }
    }
    // sXH (h) protected by the first B-chunk barrier.

    // ---- phase B: MLP. Wave grid: wr x wc over 64x128 ----
    const u16* wUp = ws + WUP_T + (size_t)g * 65536;
    const u16* wDn = ws + WDN_T + (size_t)g * 65536;

    f32x16 dacc = (f32x16)0.f;

    for (int ch = 0; ch < 4; ++ch) {
        const int c0 = ch * 128;
        __syncthreads();   // sW free; (ch0) h writes + sZ readers done
        for (int idx = tid; idx < 128 * 16; idx += 512) {   // W_upT chunk [c][k]
            int row = idx >> 4, slot = idx & 15;
            short8 v = *(const short8*)(wUp + (size_t)(c0 + row) * 128 + slot * 8);
            *(short8*)((char*)sW + swz256(row, slot * 16)) = v;
        }
        __syncthreads();

        f32x16 uacc = (f32x16)0.f;
        #pragma unroll
        for (int ks = 0; ks < 8; ++ks) {
            short8 a = fragLd256(sXH, 32 * wr + l31, ks);
            short8 b = fragLd256(sW, 32 * wc + l31, ks);
            uacc = MFMA(a, b, uacc);
        }
        {
            float bup = b_up[(size_t)g * 512 + c0 + 32 * wc + l31];
            int colB = (32 * wc + l31) * 2;
            #pragma unroll
            for (int r = 0; r < 16; ++r) {
                int row = 32 * wr + (r & 3) + 8 * (r >> 2) + 4 * lh;
                float gel = gelu_f(uacc[r] + bup);
                *(u16*)((char*)sU + swz256(row, colB)) = f2b(gel);
            }
        }
        __syncthreads();   // sU (gelu) ready; sW (up) readers done
        for (int idx = tid; idx < 128 * 16; idx += 512) {   // W_downT chunk [j][c-slice]
            int row = idx >> 4, slot = idx & 15;
            short8 v = *(const short8*)(wDn + (size_t)row * 512 + c0 + slot * 8);
            *(short8*)((char*)sW + swz256(row, slot * 16)) = v;
        }
        __syncthreads();
        #pragma unroll
        for (int ks = 0; ks < 8; ++ks) {
            short8 a = fragLd256(sU, 32 * wr + l31, ks);
            short8 b = fragLd256(sW, 32 * wc + l31, ks);
            dacc = MFMA(a, b, dacc);
        }
    }

    // epilogue: x_out = x(reg) + b_down + mlp -> global f32 + sXH bf16 (in-place)
    {
        int jc = 32 * wc + l31;
        float bd = b_down[g * 128 + jc];
        #pragma unroll
        for (int r = 0; r < 16; ++r) {
            int row = 32 * wr + (r & 3) + 8 * (r >> 2) + 4 * lh;
            size_t base = (size_t)(m0 + row) * 8192 + g * 128 + jc;
            float xo = xres[r] + bd + dacc[r];
            out[OFF_XOUT + base] = xo;
            *(u16*)((char*)sXH + swz256(row, jc * 2)) = f2b(xo);
        }
    }

    // ---- phase C: post-proj, direct from accumulator regs ----
    for (int s = 0; s < 4; ++s) {
        __syncthreads();   // sXH(x_out) ready / prev slice sW readers done
        for (int idx = tid; idx < 128 * 16; idx += 512) {   // W_postT slice [c][k]
            int row = idx >> 4, slot = idx & 15;
            short8 v = *(const short8*)(wPo + (size_t)(s * 128 + row) * 128 + slot * 8);
            *(short8*)((char*)sW + swz256(row, slot * 16)) = v;
        }
        __syncthreads();

        f32x16 acc = (f32x16)0.f;
        #pragma unroll
        for (int ks = 0; ks < 8; ++ks) {
            short8 a = fragLd256(sXH, 32 * wr + l31, ks);
            short8 b = fragLd256(sW, 32 * wc + l31, ks);
            acc = MFMA(a, b, acc);
        }
        const float bp = b_post[g * 513 + s * 128 + 32 * wc + l31];
        const int jc = 32 * wc + l31;

        if (s == 0 || s == 2) {
            float pv[16];
            #pragma unroll
            for (int r = 0; r < 16; ++r) pv[r] = acc[r] + bp;
            #pragma unroll
            for (int r = 0; r < 16; ++r) {
                float q = pv[r] * pv[r];
                q += __shfl_xor(q, 1); q += __shfl_xor(q, 2); q += __shfl_xor(q, 4);
                q += __shfl_xor(q, 8); q += __shfl_xor(q, 16);
                if (l31 == 0)
                    sNrm2[32 * wr + (r & 3) + 8 * (r >> 2) + 4 * lh][wc] = q;
            }
            __syncthreads();
            if (tid < 64) {
                float4 v = *(const float4*)&sNrm2[tid][0];
                sInv[tid] = __fdividef(1.f, sqrtf(v.x + v.y + v.z + v.w) + 1e-6f);
            }
            __syncthreads();
            size_t off = (s == 0) ? OFF_KC : OFF_QN;
            #pragma unroll
            for (int r = 0; r < 16; ++r) {
                int row = 32 * wr + (r & 3) + 8 * (r >> 2) + 4 * lh;
                out[off + (size_t)(m0 + row) * 8192 + g * 128 + jc] = pv[r] * sInv[row];
            }
        } else {
            size_t off = (s == 1) ? OFF_VP : OFF_VC;
            #pragma unroll
            for (int r = 0; r < 16; ++r) {
                int row = 32 * wr + (r & 3) + 8 * (r >> 2) + 4 * lh;
                out[off + (size_t)(m0 + row) * 8192 + g * 128 + jc] = acc[r] + bp;
            }
        }
    }

    // nov column -> w_nov (x_out bf16 in sXH; no writes to sXH since epilogue)
    {
        int row = tid >> 3, part = tid & 7;   // 64 rows x 8 parts
        float accn = 0.f;
        #pragma unroll
        for (int i = 0; i < 2; ++i) {
            short8 v = *(const short8*)((const char*)sXH + swz256(row, (part * 16 + i * 8) * 2));
            #pragma unroll
            for (int jj = 0; jj < 8; ++jj) accn += b2f((u16)v[jj]) * sNov[part * 16 + i * 8 + jj];
        }
        accn += __shfl_xor(accn, 1); accn += __shfl_xor(accn, 2); accn += __shfl_xor(accn, 4);
        if (part == 0) {
            float nv = accn + b_post[g * 513 + 512];
            out[OFF_WN + (size_t)(m0 + row) * 64 + g] = __fdividef(1.f, 1.f + __expf(-nv));
        }
    }
}

extern "C" void kernel_launch(void* const* d_in, const int* in_sizes, int n_in,
                              void* d_out, int out_size, void* d_ws, size_t ws_size,
                              hipStream_t stream) {
    const float* x_col      = (const float*)d_in[0];
    const float* z_hat_prev = (const float*)d_in[1];
    const float* gamma      = (const float*)d_in[2];
    const float* beta       = (const float*)d_in[3];
    const float* W_up       = (const float*)d_in[4];
    const float* b_up       = (const float*)d_in[5];
    const float* W_down     = (const float*)d_in[6];
    const float* b_down     = (const float*)d_in[7];
    const float* W_post     = (const float*)d_in[8];
    const float* b_post     = (const float*)d_in[9];
    const float* W_enc      = (const float*)d_in[10];
    const float* b_enc      = (const float*)d_in[11];
    const float* W_pred     = (const float*)d_in[12];
    const float* b_pred     = (const float*)d_in[13];
    const float* W_gain     = (const float*)d_in[14];
    const float* b_gain     = (const float*)d_in[15];
    float* out = (float*)d_out;
    u16* ws = (u16*)d_ws;

    kconv_all<<<3520, 256, 0, stream>>>(W_up, W_down, W_post, W_enc, W_gain, W_pred, ws);
    kfused<<<2048, 512, 0, stream>>>(x_col, z_hat_prev, gamma, beta,
                                     b_enc, b_pred, b_gain, b_up, b_down, b_post,
                                     ws, out);
}

// Round 8
// 384.426 us; speedup vs baseline: 1.2100x; 1.2100x over previous
//
#include <hip/hip_runtime.h>

typedef unsigned short u16;
typedef __attribute__((ext_vector_type(4))) unsigned short u16x4;
typedef __attribute__((ext_vector_type(8))) short short8;
typedef __attribute__((ext_vector_type(16))) float f32x16;

#define MFMA(a,b,c) __builtin_amdgcn_mfma_f32_32x32x16_bf16((a),(b),(c),0,0,0)

// ---- output offsets (floats), reference return order ----
static constexpr size_t OFF_XOUT = 0;
static constexpr size_t OFF_Z    = 16777216;
static constexpr size_t OFF_ZHAT = 20971520;
static constexpr size_t OFF_SUR  = 25165824;
static constexpr size_t OFF_KC   = 25296896;
static constexpr size_t OFF_VP   = 42074112;
static constexpr size_t OFF_GATE = 58851328;
static constexpr size_t OFF_QN   = 58982400;
static constexpr size_t OFF_VC   = 75759616;
static constexpr size_t OFF_WN   = 92536832;
static constexpr size_t OFF_S5   = 92667904;

// ---- workspace offsets (u16 elements): transposed bf16 weights ----
static constexpr size_t WUP_T = 0;          // [G][512][128]
static constexpr size_t WDN_T = 4194304;    // [G][128][512]
static constexpr size_t WPO_T = 8388608;    // [G][513][128]
static constexpr size_t WEN_T = 12591104;   // [G][32][128]
static constexpr size_t WGN_T = 12853248;   // [G][128][32]
static constexpr size_t WPR_T = 13115392;   // [G][32][32]

__device__ __forceinline__ u16 f2b(float f) {
    unsigned u = __float_as_uint(f);
    unsigned r = (u + 0x7FFFu + ((u >> 16) & 1u)) >> 16;
    return (u16)r;
}
__device__ __forceinline__ float b2f(u16 b) {
    return __uint_as_float(((unsigned)b) << 16);
}
// swizzles: 256B rows, 128B rows, 64B rows
__device__ __forceinline__ int swz256(int row, int b) {
    return row * 256 + (b ^ ((row & 7) << 4) ^ (((row >> 3) & 1) << 7));
}
__device__ __forceinline__ int swz128(int row, int b) {
    return row * 128 + (b ^ ((row & 7) << 4));
}
__device__ __forceinline__ int swz64(int row, int b) {
    return row * 64 + (b ^ ((row & 3) << 4));
}
__device__ __forceinline__ short8 fragLd256(const u16* s, int row, int ks) {
    int b = ks * 32 + ((threadIdx.x >> 5) & 1) * 16;
    return *(const short8*)((const char*)s + swz256(row, b));
}
__device__ __forceinline__ short8 fragLd128(const u16* s, int row, int ks) {
    int b = ks * 32 + ((threadIdx.x >> 5) & 1) * 16;
    return *(const short8*)((const char*)s + swz128(row, b));
}
__device__ __forceinline__ short8 fragLd64(const u16* s, int row, int ks) {
    int b = ks * 32 + ((threadIdx.x >> 5) & 1) * 16;
    return *(const short8*)((const char*)s + swz64(row, b));
}
// direct-from-global B-fragment (W^T [C][K] row-major, L2-resident small weights)
__device__ __forceinline__ short8 gfrag(const u16* wT, int row, int ldk, int ks) {
    int lh = (threadIdx.x >> 5) & 1;
    return *(const short8*)(wT + (size_t)row * ldk + ks * 16 + lh * 8);
}
__device__ __forceinline__ float tanh_f(float x) {
    float xc = fminf(fmaxf(x, -15.f), 15.f);
    float e = __expf(2.f * xc);
    return __fdividef(e - 1.f, e + 1.f);
}
__device__ __forceinline__ float gelu_f(float u) {
    float y = 0.7978845608f * (u + 0.044715f * u * u * u);
    return 0.5f * u * (1.f + tanh_f(y));
}

// ---------------- fused transpose+convert for all six weights ----------------
__global__ __launch_bounds__(256)
void kconv_all(const float* __restrict__ W_up, const float* __restrict__ W_down,
               const float* __restrict__ W_post, const float* __restrict__ W_enc,
               const float* __restrict__ W_gain, const float* __restrict__ W_pred,
               u16* __restrict__ ws)
{
    int b = blockIdx.x;
    const float* src; u16* dst; int K, C, bx;
    if (b < 1024)      { src = W_up;   dst = ws + WUP_T; K = 128; C = 512; bx = 8; }
    else if (b < 2048) { b -= 1024; src = W_down; dst = ws + WDN_T; K = 512; C = 128; bx = 2; }
    else if (b < 3200) { b -= 2048; src = W_post; dst = ws + WPO_T; K = 128; C = 513; bx = 9; }
    else if (b < 3328) { b -= 3200; src = W_enc;  dst = ws + WEN_T; K = 128; C = 32;  bx = 1; }
    else if (b < 3456) { b -= 3328; src = W_gain; dst = ws + WGN_T; K = 32;  C = 128; bx = 2; }
    else               { b -= 3456; src = W_pred; dst = ws + WPR_T; K = 32;  C = 32;  bx = 1; }
    const int by = (K + 63) >> 6;
    const int nb = bx * by;
    const int g = b / nb, r = b % nb;
    const int c0 = (r % bx) * 64, k0 = (r / bx) * 64;

    __shared__ float sT[64][65];
    const float* s = src + (size_t)g * K * C;
    u16* d = dst + (size_t)g * K * C;
    for (int e = threadIdx.x; e < 64 * 64; e += 256) {
        int kk = e >> 6, cc = e & 63;
        if (k0 + kk < K && c0 + cc < C)
            sT[kk][cc] = s[(size_t)(k0 + kk) * C + c0 + cc];
    }
    __syncthreads();
    for (int e = threadIdx.x; e < 64 * 64; e += 256) {
        int cc = e >> 6, kk = e & 63;
        if (k0 + kk < K && c0 + cc < C)
            d[(size_t)(c0 + cc) * K + k0 + kk] = f2b(sT[kk][cc]);
    }
}

// ---------------- fused main: 128-token tile, 512 threads, ~67KB LDS ----------------
__global__ __launch_bounds__(512, 4)
void kfused(const float* __restrict__ x_col,
            const float* __restrict__ z_hat_prev,
            const float* __restrict__ gamma,
            const float* __restrict__ beta,
            const float* __restrict__ b_enc,
            const float* __restrict__ b_pred,
            const float* __restrict__ b_gain,
            const float* __restrict__ b_up,
            const float* __restrict__ b_down,
            const float* __restrict__ b_post,
            const u16* __restrict__ ws,
            float* __restrict__ out)
{
    const int bid = blockIdx.x;
    const int xc = bid & 7, j = bid >> 3;    // 1024 blocks
    const int g = xc * 8 + (j >> 4);
    const int tile = j & 15;
    const int m0 = tile * 128;

    const int tid = threadIdx.x, lane = tid & 63;
    const int w8 = tid >> 6;                 // wave 0..7
    const int wfr = w8 >> 1;                 // row frag 0..3 (32 rows each)
    const int wfc = w8 & 1;                  // col group 0..1 (64 cols each)
    const int l31 = lane & 31, lh = lane >> 5;

    __shared__ u16 sXH[16384];      // 32KB: x -> h -> x_out (in place, swz256)
    __shared__ u16 sPool[16384];    // 32KB: A: sD/sZ; B: Wchunk+U; C: Wpost slice
    __shared__ float sMu[128], sRstd[128], sInv[128], sNov[128];
    __shared__ float sNrm2[128][2];

    u16* sD = sPool;                // [128][32] swz64 (8KB)
    u16* sZ = sPool + 4096;         // [128][32] swz64 (8KB)
    u16* sA = sPool;                // B: weight chunk (16KB)
    u16* sB = sPool + 8192;         // B: gelu-U chunk [128][64] swz128 (16KB)

    const u16* wPo = ws + WPO_T + (size_t)g * 65664;
    const u16* wEn = ws + WEN_T + (size_t)g * 4096;
    const u16* wGn = ws + WGN_T + (size_t)g * 4096;
    const u16* wPr = ws + WPR_T + (size_t)g * 1024;

    // ---- stage x -> sXH bf16 swz256 ----
    for (int idx = tid; idx < 128 * 32; idx += 512) {
        int row = idx >> 5, q = idx & 31;
        float4 v = *(const float4*)&x_col[(size_t)(m0 + row) * 8192 + g * 128 + q * 4];
        u16x4 bv; bv.x = f2b(v.x); bv.y = f2b(v.y); bv.z = f2b(v.z); bv.w = f2b(v.w);
        *(u16x4*)((char*)sXH + swz256(row, q * 8)) = bv;
    }
    if (tid < 128) sNov[tid] = b2f(wPo[(size_t)512 * 128 + tid]);
    __syncthreads();

    // ---- phase A step 1: {waves 0-3: enc} || {waves 4-7: LN stats} ----
    if (w8 < 4) {
        f32x16 zacc = (f32x16)0.f;
        #pragma unroll
        for (int ks = 0; ks < 8; ++ks)
            zacc = MFMA(fragLd256(sXH, 32 * w8 + l31, ks), gfrag(wEn, l31, 128, ks), zacc);
        float benc = b_enc[g * 32 + l31];
        #pragma unroll
        for (int r = 0; r < 16; ++r) {
            float zv = zacc[r] + benc;
            int row = 32 * w8 + (r & 3) + 8 * (r >> 2) + 4 * lh;
            size_t zoff = (size_t)(m0 + row) * 2048 + g * 32 + l31;
            out[OFF_Z + zoff] = zv;
            float d = zv - z_hat_prev[zoff];
            *(u16*)((char*)sD + swz64(row, l31 * 2)) = f2b(d);
            *(u16*)((char*)sZ + swz64(row, l31 * 2)) = f2b(zv);
            float ss = d * d;
            ss += __shfl_xor(ss, 1); ss += __shfl_xor(ss, 2); ss += __shfl_xor(ss, 4);
            ss += __shfl_xor(ss, 8); ss += __shfl_xor(ss, 16);
            if (l31 == 0) {
                float sur = sqrtf(ss);
                size_t p = (size_t)(m0 + row) * 64 + g;
                out[OFF_SUR + p] = sur;
                out[OFF_S5 + p] = sur;
                out[OFF_GATE + p] = fminf(fmaxf(sur, 0.f), 1.f);
            }
        }
    } else {
        int t = tid - 256;
        int row = t >> 1, half = t & 1;
        float s1 = 0.f, s2 = 0.f;
        #pragma unroll
        for (int i = 0; i < 8; ++i) {
            short8 v = *(const short8*)((const char*)sXH + swz256(row, (half * 64 + i * 8) * 2));
            #pragma unroll
            for (int jj = 0; jj < 8; ++jj) { float x = b2f((u16)v[jj]); s1 += x; s2 += x * x; }
        }
        s1 += __shfl_xor(s1, 1); s2 += __shfl_xor(s2, 1);
        if (half == 0) {
            float mu = s1 * (1.f / 128.f);
            float var = s2 * (1.f / 128.f) - mu * mu;
            sMu[row] = mu; sRstd[row] = rsqrtf(var + 1e-5f);
        }
    }
    __syncthreads();

    // ---- phase A step 2: {waves 0-3: pred} then {all waves: gain + LN apply} ----
    if (w8 < 4) {
        f32x16 pacc = (f32x16)0.f;
        #pragma unroll
        for (int ks = 0; ks < 2; ++ks)
            pacc = MFMA(fragLd64(sZ, 32 * w8 + l31, ks), gfrag(wPr, l31, 32, ks), pacc);
        float bpred = b_pred[g * 32 + l31];
        #pragma unroll
        for (int r = 0; r < 16; ++r) {
            int row = 32 * w8 + (r & 3) + 8 * (r >> 2) + 4 * lh;
            out[OFF_ZHAT + (size_t)(m0 + row) * 2048 + g * 32 + l31] = pacc[r] + bpred;
        }
    }
    {   // gain: all 8 waves, 2 col-frags each (rows 32*wfr, cols 64*wfc..)
        f32x16 gacc[2];
        gacc[0] = (f32x16)0.f; gacc[1] = (f32x16)0.f;
        #pragma unroll
        for (int ks = 0; ks < 2; ++ks) {
            short8 a = fragLd64(sD, 32 * wfr + l31, ks);
            #pragma unroll
            for (int k = 0; k < 2; ++k)
                gacc[k] = MFMA(a, gfrag(wGn, 32 * (2 * wfc + k) + l31, 32, ks), gacc[k]);
        }
        #pragma unroll
        for (int k = 0; k < 2; ++k) {
            int col = 32 * (2 * wfc + k) + l31;
            float bg = b_gain[g * 128 + col];
            float gam = gamma[g * 128 + col];
            float bet = beta[g * 128 + col];
            #pragma unroll
            for (int r = 0; r < 16; ++r) {
                int row = 32 * wfr + (r & 3) + 8 * (r >> 2) + 4 * lh;
                float gain = 1.f + 0.1f * tanh_f(gacc[k][r] + bg);
                float xv = b2f(*(const u16*)((const char*)sXH + swz256(row, col * 2)));
                float h = ((xv - sMu[row]) * sRstd[row] * gam + bet) * gain;
                *(u16*)((char*)sXH + swz256(row, col * 2)) = f2b(h);   // in place
            }
        }
    }

    // residual fragments in registers (f32 exact), overlap with phase B
    float xres[2][16];
    #pragma unroll
    for (int f = 0; f < 2; ++f)
        #pragma unroll
        for (int r = 0; r < 16; ++r) {
            int row = 32 * wfr + (r & 3) + 8 * (r >> 2) + 4 * lh;
            xres[f][r] = x_col[(size_t)(m0 + row) * 8192 + g * 128 + 64 * wfc + 32 * f + l31];
        }

    // ---- phase B: MLP in 8 chunks of 64 hidden cols ----
    const u16* wUp = ws + WUP_T + (size_t)g * 65536;
    const u16* wDn = ws + WDN_T + (size_t)g * 65536;

    f32x16 dacc[2];
    dacc[0] = (f32x16)0.f; dacc[1] = (f32x16)0.f;

    for (int ch = 0; ch < 8; ++ch) {
        const int c0 = ch * 64;
        __syncthreads();   // prev chunk's sA/sB readers done; (ch0) sD/sZ readers done
        for (int idx = tid; idx < 64 * 16; idx += 512) {   // Wup chunk [64c][128k] swz256
            int row = idx >> 4, slot = idx & 15;
            short8 v = *(const short8*)(wUp + (size_t)(c0 + row) * 128 + slot * 8);
            *(short8*)((char*)sA + swz256(row, slot * 16)) = v;
        }
        __syncthreads();
        // up: out [128][64], 1 frag/wave (rows 32*wfr, cols 32*wfc)
        f32x16 uacc = (f32x16)0.f;
        #pragma unroll
        for (int ks = 0; ks < 8; ++ks)
            uacc = MFMA(fragLd256(sXH, 32 * wfr + l31, ks),
                        fragLd256(sA, 32 * wfc + l31, ks), uacc);
        {
            float bup = b_up[(size_t)g * 512 + c0 + 32 * wfc + l31];
            int colB = (32 * wfc + l31) * 2;
            #pragma unroll
            for (int r = 0; r < 16; ++r) {
                int row = 32 * wfr + (r & 3) + 8 * (r >> 2) + 4 * lh;
                *(u16*)((char*)sB + swz128(row, colB)) = f2b(gelu_f(uacc[r] + bup));
            }
        }
        __syncthreads();   // gelu done; sA (Wup) readers done
        for (int idx = tid; idx < 128 * 8; idx += 512) {   // Wdn chunk [128j][64c] swz128
            int row = idx >> 3, blk = idx & 7;
            short8 v = *(const short8*)(wDn + (size_t)row * 512 + c0 + blk * 8);
            *(short8*)((char*)sA + swz128(row, blk * 16)) = v;
        }
        __syncthreads();
        // down: out [128][128], 2 frags/wave (rows 32*wfr, cols 64*wfc+32f), K=64
        #pragma unroll
        for (int f = 0; f < 2; ++f)
            #pragma unroll
            for (int ks = 0; ks < 4; ++ks)
                dacc[f] = MFMA(fragLd128(sB, 32 * wfr + l31, ks),
                               fragLd128(sA, 64 * wfc + 32 * f + l31, ks), dacc[f]);
    }
    __syncthreads();   // all sXH readers (up-MFMA) done before overwrite

    // epilogue: x_out = x(reg) + b_down + mlp -> global f32 + sXH bf16
    #pragma unroll
    for (int f = 0; f < 2; ++f) {
        int jc = 64 * wfc + 32 * f + l31;
        float bd = b_down[g * 128 + jc];
        #pragma unroll
        for (int r = 0; r < 16; ++r) {
            int row = 32 * wfr + (r & 3) + 8 * (r >> 2) + 4 * lh;
            size_t base = (size_t)(m0 + row) * 8192 + g * 128 + jc;
            float xo = xres[f][r] + bd + dacc[f][r];
            out[OFF_XOUT + base] = xo;
            *(u16*)((char*)sXH + swz256(row, jc * 2)) = f2b(xo);
        }
    }

    // ---- phase C: post-proj, 4 slices of 128 cols staged across full sPool ----
    for (int s = 0; s < 4; ++s) {
        __syncthreads();   // sXH(x_out) ready / prev slice readers done
        for (int idx = tid; idx < 128 * 16; idx += 512) {   // Wpost slice [128c][128k] swz256
            int row = idx >> 4, slot = idx & 15;
            short8 v = *(const short8*)(wPo + (size_t)(s * 128 + row) * 128 + slot * 8);
            *(short8*)((char*)sPool + swz256(row, slot * 16)) = v;
        }
        __syncthreads();

        f32x16 acc[2];
        acc[0] = (f32x16)0.f; acc[1] = (f32x16)0.f;
        #pragma unroll
        for (int f = 0; f < 2; ++f)
            #pragma unroll
            for (int ks = 0; ks < 8; ++ks)
                acc[f] = MFMA(fragLd256(sXH, 32 * wfr + l31, ks),
                              fragLd256(sPool, 64 * wfc + 32 * f + l31, ks), acc[f]);

        float bp0 = b_post[g * 513 + s * 128 + 64 * wfc + l31];
        float bp1 = b_post[g * 513 + s * 128 + 64 * wfc + 32 + l31];

        if (s == 0 || s == 2) {
            float pv[2][16];
            #pragma unroll
            for (int r = 0; r < 16; ++r) { pv[0][r] = acc[0][r] + bp0; pv[1][r] = acc[1][r] + bp1; }
            #pragma unroll
            for (int r = 0; r < 16; ++r) {
                float q = pv[0][r] * pv[0][r] + pv[1][r] * pv[1][r];
                q += __shfl_xor(q, 1); q += __shfl_xor(q, 2); q += __shfl_xor(q, 4);
                q += __shfl_xor(q, 8); q += __shfl_xor(q, 16);
                if (l31 == 0)
                    sNrm2[32 * wfr + (r & 3) + 8 * (r >> 2) + 4 * lh][wfc] = q;
            }
            __syncthreads();
            if (tid < 128)
                sInv[tid] = __fdividef(1.f, sqrtf(sNrm2[tid][0] + sNrm2[tid][1]) + 1e-6f);
            __syncthreads();
            size_t off = (s == 0) ? OFF_KC : OFF_QN;
            #pragma unroll
            for (int f = 0; f < 2; ++f) {
                int jc = 64 * wfc + 32 * f + l31;
                #pragma unroll
                for (int r = 0; r < 16; ++r) {
                    int row = 32 * wfr + (r & 3) + 8 * (r >> 2) + 4 * lh;
                    out[off + (size_t)(m0 + row) * 8192 + g * 128 + jc] = pv[f][r] * sInv[row];
                }
            }
        } else {
            size_t off = (s == 1) ? OFF_VP : OFF_VC;
            #pragma unroll
            for (int f = 0; f < 2; ++f) {
                int jc = 64 * wfc + 32 * f + l31;
                float bp = (f == 0) ? bp0 : bp1;
                #pragma unroll
                for (int r = 0; r < 16; ++r) {
                    int row = 32 * wfr + (r & 3) + 8 * (r >> 2) + 4 * lh;
                    out[off + (size_t)(m0 + row) * 8192 + g * 128 + jc] = acc[f][r] + bp;
                }
            }
        }
    }

    // nov column -> w_nov (x_out bf16 in sXH)
    {
        int row = tid >> 2, part = tid & 3;   // 128 rows x 4 parts (32 cols each)
        float accn = 0.f;
        #pragma unroll
        for (int i = 0; i < 4; ++i) {
            short8 v = *(const short8*)((const char*)sXH + swz256(row, (part * 32 + i * 8) * 2));
            #pragma unroll
            for (int jj = 0; jj < 8; ++jj) accn += b2f((u16)v[jj]) * sNov[part * 32 + i * 8 + jj];
        }
        accn += __shfl_xor(accn, 1); accn += __shfl_xor(accn, 2);
        if (part == 0) {
            float nv = accn + b_post[g * 513 + 512];
            out[OFF_WN + (size_t)(m0 + row) * 64 + g] = __fdividef(1.f, 1.f + __expf(-nv));
        }
    }
}

extern "C" void kernel_launch(void* const* d_in, const int* in_sizes, int n_in,
                              void* d_out, int out_size, void* d_ws, size_t ws_size,
                              hipStream_t stream) {
    const float* x_col      = (const float*)d_in[0];
    const float* z_hat_prev = (const float*)d_in[1];
    const float* gamma      = (const float*)d_in[2];
    const float* beta       = (const float*)d_in[3];
    const float* W_up       = (const float*)d_in[4];
    const float* b_up       = (const float*)d_in[5];
    const float* W_down     = (const float*)d_in[6];
    const float* b_down     = (const float*)d_in[7];
    const float* W_post     = (const float*)d_in[8];
    const float* b_post     = (const float*)d_in[9];
    const float* W_enc      = (const float*)d_in[10];
    const float* b_enc      = (const float*)d_in[11];
    const float* W_pred     = (const float*)d_in[12];
    const float* b_pred     = (const float*)d_in[13];
    const float* W_gain     = (const float*)d_in[14];
    const float* b_gain     = (const float*)d_in[15];
    float* out = (float*)d_out;
    u16* ws = (u16*)d_ws;

    kconv_all<<<3520, 256, 0, stream>>>(W_up, W_down, W_post, W_enc, W_gain, W_pred, ws);
    kfused<<<1024, 512, 0, stream>>>(x_col, z_hat_prev, gamma, beta,
                                     b_enc, b_pred, b_gain, b_up, b_down, b_post,
                                     ws, out);
}